// Round 2
// baseline (1311.692 us; speedup 1.0000x reference)
//
#include <hip/hip_runtime.h>
#include <hip/hip_bf16.h>

// Problem: B=1024, N=256, C=1024, OUT=1
//   s[b,c]   = sum_n x[b,n,c]
//   h[b,:]   = LayerNorm_C(s[b,:]) * ln_w + ln_b
//   out[b]   = sigmoid(dot(h[b,:], W[0,:]) + bias)
//
// Memory-bound: one 1 GiB read of x. One block per b; 256 threads x float4
// (each thread owns 4 channels), n-loop over 256 contiguous 4 KiB rows.
// Round 1: identical resubmit — Round 0 hit GPUAcquisitionTimeout (no data).

#define BATCH 1024
#define NNODE 256
#define NCHAN 1024
#define LN_EPS 1e-5f

__global__ __launch_bounds__(256) void fused_reduce_ln_linear_sigmoid(
    const float* __restrict__ x,
    const float* __restrict__ ln_w,
    const float* __restrict__ ln_b,
    const float* __restrict__ W,
    const float* __restrict__ bias,
    float* __restrict__ out) {
  const int b = blockIdx.x;
  const int t = threadIdx.x;        // 0..255
  const int lane = t & 63;
  const int wid = t >> 6;           // 0..3 (4 waves)

  // ---- 1) reduce over N: each thread accumulates 4 channels [4t..4t+3] ----
  const float* xb = x + (size_t)b * NNODE * NCHAN + (size_t)t * 4;
  float ax = 0.f, ay = 0.f, az = 0.f, aw = 0.f;
  float bx = 0.f, by = 0.f, bz = 0.f, bw = 0.f;  // 2nd accumulator: shorter dep chain
#pragma unroll 4
  for (int n = 0; n < NNODE; n += 2) {
    float4 v0 = *reinterpret_cast<const float4*>(xb + (size_t)n * NCHAN);
    float4 v1 = *reinterpret_cast<const float4*>(xb + (size_t)(n + 1) * NCHAN);
    ax += v0.x; ay += v0.y; az += v0.z; aw += v0.w;
    bx += v1.x; by += v1.y; bz += v1.z; bw += v1.w;
  }
  const float s0 = ax + bx, s1 = ay + by, s2 = az + bz, s3 = aw + bw;

  // ---- 2) block reduction for LN stats (sum, sumsq over C=1024) ----
  float psum = s0 + s1 + s2 + s3;
  float psq  = s0 * s0 + s1 * s1 + s2 * s2 + s3 * s3;
#pragma unroll
  for (int off = 32; off; off >>= 1) {
    psum += __shfl_down(psum, off);
    psq  += __shfl_down(psq, off);
  }
  __shared__ float ssum[4], ssq[4], sdot[4];
  if (lane == 0) { ssum[wid] = psum; ssq[wid] = psq; }
  __syncthreads();
  const float tot = ssum[0] + ssum[1] + ssum[2] + ssum[3];
  const float tsq = ssq[0] + ssq[1] + ssq[2] + ssq[3];
  const float mu   = tot * (1.0f / NCHAN);
  const float var  = tsq * (1.0f / NCHAN) - mu * mu;
  const float rstd = rsqrtf(var + LN_EPS);

  // ---- 3) LN affine + dot with W ----
  const int c0 = t * 4;
  const float4 w4 = *reinterpret_cast<const float4*>(W + c0);
  const float4 lw = *reinterpret_cast<const float4*>(ln_w + c0);
  const float4 lb = *reinterpret_cast<const float4*>(ln_b + c0);
  float dot = ((s0 - mu) * rstd * lw.x + lb.x) * w4.x
            + ((s1 - mu) * rstd * lw.y + lb.y) * w4.y
            + ((s2 - mu) * rstd * lw.z + lb.z) * w4.z
            + ((s3 - mu) * rstd * lw.w + lb.w) * w4.w;
#pragma unroll
  for (int off = 32; off; off >>= 1) dot += __shfl_down(dot, off);
  if (lane == 0) sdot[wid] = dot;
  __syncthreads();

  // ---- 4) sigmoid + store ----
  if (t == 0) {
    const float logit = sdot[0] + sdot[1] + sdot[2] + sdot[3] + bias[0];
    out[b] = 1.0f / (1.0f + expf(-logit));
  }
}

extern "C" void kernel_launch(void* const* d_in, const int* in_sizes, int n_in,
                              void* d_out, int out_size, void* d_ws, size_t ws_size,
                              hipStream_t stream) {
  const float* x    = (const float*)d_in[0];
  const float* ln_w = (const float*)d_in[1];
  const float* ln_b = (const float*)d_in[2];
  const float* W    = (const float*)d_in[3];
  const float* bias = (const float*)d_in[4];
  float* out        = (float*)d_out;

  fused_reduce_ln_linear_sigmoid<<<BATCH, 256, 0, stream>>>(
      x, ln_w, ln_b, W, bias, out);
}